// Round 3
// baseline (192.233 us; speedup 1.0000x reference)
//
#include <hip/hip_runtime.h>

// FComb: fused pointwise 4-layer MLP over 96^3 points, bf16 MFMA version.
// R3: latency fix — GPW=2, both point-groups' global loads issued at kernel
// entry (32 x 8B in flight) so HBM latency hides under weight/bias setup and
// group-a compute. Compute body identical to R2 (verified absmax 7.8e-3).
// D layout (m74/m101): col=lane&31 (point), row=(r&3)+8*(r>>2)+4*(lane>>5).

typedef float  f32x16 __attribute__((ext_vector_type(16)));
typedef short  bf16x8 __attribute__((ext_vector_type(8)));

constexpr int NPTS   = 96 * 96 * 96;   // 884736
constexpr int NP2    = NPTS / 2;       // float2 count per channel
constexpr int BLOCK  = 256;            // 4 waves
constexpr int GPW    = 2;              // 64-pt groups per wave
constexpr int NBLK   = 1728;           // 6912 waves * 2 * 64 = NPTS

union FragU { unsigned u[4]; bf16x8 v; };

__device__ inline unsigned cvtpk(float lo, float hi) {
    unsigned d;
    asm("v_cvt_pk_bf16_f32 %0, %1, %2" : "=v"(d) : "v"(lo), "v"(hi));
    return d;
}
__device__ inline float unlo(unsigned d) { return __uint_as_float(d << 16); }
__device__ inline float unhi(unsigned d) { return __uint_as_float(d & 0xffff0000u); }

__device__ inline bf16x8 mk(unsigned d0, unsigned d1, unsigned d2, unsigned d3) {
    FragU f; f.u[0] = d0; f.u[1] = d1; f.u[2] = d2; f.u[3] = d3; return f.v;
}

__device__ inline void swap32(unsigned a, unsigned b, unsigned& x, unsigned& y) {
    auto r = __builtin_amdgcn_permlane32_swap(a, b, false, false);
    x = r[0]; y = r[1];
}

__device__ inline bf16x8 load_wfrag(const float* __restrict__ W, int stride,
                                    int row, int koff) {
    const float2* W2 = reinterpret_cast<const float2*>(W + row * stride + koff);
    float2 a = W2[0], b = W2[1], c = W2[2], d = W2[3];
    return mk(cvtpk(a.x, a.y), cvtpk(b.x, b.y), cvtpk(c.x, c.y), cvtpk(d.x, d.y));
}

__device__ inline void build_bfrags(const float* h,
                                    bf16x8& B0h, bf16x8& B0l,
                                    bf16x8& B1h, bf16x8& B1l) {
    unsigned hp[8], lp[8];
    #pragma unroll
    for (int j = 0; j < 8; ++j) {
        float h0 = fmaxf(h[2 * j], 0.f), h1 = fmaxf(h[2 * j + 1], 0.f);
        unsigned d = cvtpk(h0, h1);
        hp[j] = d;
        lp[j] = cvtpk(h0 - unlo(d), h1 - unhi(d));
    }
    unsigned a0, a1, b0, b1, c0, c1, d0, d1;
    swap32(hp[0], hp[2], a0, a1); swap32(hp[1], hp[3], b0, b1);
    swap32(hp[4], hp[6], c0, c1); swap32(hp[5], hp[7], d0, d1);
    B0h = mk(a0, b0, a1, b1);
    B1h = mk(c0, d0, c1, d1);
    swap32(lp[0], lp[2], a0, a1); swap32(lp[1], lp[3], b0, b1);
    swap32(lp[4], lp[6], c0, c1); swap32(lp[5], lp[7], d0, d1);
    B0l = mk(a0, b0, a1, b1);
    B1l = mk(c0, d0, c1, d1);
}

__global__ __launch_bounds__(BLOCK, 2)
void fused_mlp_mfma(const float* __restrict__ fm, const float* __restrict__ z,
                    const float* __restrict__ w1, const float* __restrict__ b1,
                    const float* __restrict__ w2, const float* __restrict__ b2,
                    const float* __restrict__ w3, const float* __restrict__ b3,
                    const float* __restrict__ wl, const float* __restrict__ bl,
                    float* __restrict__ out)
{
    const int lane = threadIdx.x & 63;
    const int wid  = blockIdx.x * (BLOCK / 64) + (threadIdx.x >> 6);
    const int hl   = lane >> 5;
    const int col  = lane & 31;
    const int koff = 8 * hl;

    const float2* __restrict__ fm2 = reinterpret_cast<const float2*>(fm);
    float2* __restrict__ out2      = reinterpret_cast<float2*>(out);

    // ---- issue BOTH groups' input loads first: 32 x 8B in flight ----
    const int g0   = wid * GPW;
    const int pt2a = (g0 + 0) * 32 + col;
    const int pt2b = (g0 + 1) * 32 + col;
    float2 va[16], vb[16];
    #pragma unroll
    for (int i = 0; i < 16; ++i) {
        const int ch = ((i < 8) ? i : (8 + i)) + koff;
        va[i] = fm2[ch * NP2 + pt2a];
    }
    #pragma unroll
    for (int i = 0; i < 16; ++i) {
        const int ch = ((i < 8) ? i : (8 + i)) + koff;
        vb[i] = fm2[ch * NP2 + pt2b];
    }

    // ---- weight A-frags (bf16) — hides under the loads above ----
    bf16x8 W1f[2], W2f[2], W3f[2];
    #pragma unroll
    for (int h = 0; h < 2; ++h) {
        W1f[h] = load_wfrag(w1, 38, col, 16 * h + koff);
        W2f[h] = load_wfrag(w2, 32, col, 16 * h + koff);
        W3f[h] = load_wfrag(w3, 32, col, 16 * h + koff);
    }

    // ---- bias frags in D layout; z folded into b1 ----
    float zv[6];
    #pragma unroll
    for (int j = 0; j < 6; ++j) zv[j] = z[j];
    f32x16 B1f, B2f, B3f;
    float wlr[16];
    #pragma unroll
    for (int r = 0; r < 16; ++r) {
        const int ch = (r & 3) + 8 * (r >> 2) + 4 * hl;
        float t = b1[ch];
        #pragma unroll
        for (int j = 0; j < 6; ++j) t = fmaf(w1[ch * 38 + 32 + j], zv[j], t);
        B1f[r] = t;
        B2f[r] = b2[ch];
        B3f[r] = b3[ch];
        wlr[r] = wl[ch];
    }
    const float blv = bl[0];

    auto compute_group = [&](const float2* v, int pt2) {
        // ---- layer 1 (input in B-frag layout; split hi/lo) ----
        f32x16 accE = B1f, accO = B1f;
        {
            unsigned he[8], le[8], ho[8], lo_[8];
            #pragma unroll
            for (int j = 0; j < 8; ++j) {
                float e0 = v[2 * j].x, e1 = v[2 * j + 1].x;
                unsigned d = cvtpk(e0, e1);
                he[j] = d; le[j] = cvtpk(e0 - unlo(d), e1 - unhi(d));
                float o0 = v[2 * j].y, o1 = v[2 * j + 1].y;
                unsigned q = cvtpk(o0, o1);
                ho[j] = q; lo_[j] = cvtpk(o0 - unlo(q), o1 - unhi(q));
            }
            accE = __builtin_amdgcn_mfma_f32_32x32x16_bf16(W1f[0], mk(he[0], he[1], he[2], he[3]), accE, 0, 0, 0);
            accE = __builtin_amdgcn_mfma_f32_32x32x16_bf16(W1f[0], mk(le[0], le[1], le[2], le[3]), accE, 0, 0, 0);
            accE = __builtin_amdgcn_mfma_f32_32x32x16_bf16(W1f[1], mk(he[4], he[5], he[6], he[7]), accE, 0, 0, 0);
            accE = __builtin_amdgcn_mfma_f32_32x32x16_bf16(W1f[1], mk(le[4], le[5], le[6], le[7]), accE, 0, 0, 0);
            accO = __builtin_amdgcn_mfma_f32_32x32x16_bf16(W1f[0], mk(ho[0], ho[1], ho[2], ho[3]), accO, 0, 0, 0);
            accO = __builtin_amdgcn_mfma_f32_32x32x16_bf16(W1f[0], mk(lo_[0], lo_[1], lo_[2], lo_[3]), accO, 0, 0, 0);
            accO = __builtin_amdgcn_mfma_f32_32x32x16_bf16(W1f[1], mk(ho[4], ho[5], ho[6], ho[7]), accO, 0, 0, 0);
            accO = __builtin_amdgcn_mfma_f32_32x32x16_bf16(W1f[1], mk(lo_[4], lo_[5], lo_[6], lo_[7]), accO, 0, 0, 0);
        }

        // ---- layer 2 ----
        f32x16 nE, nO;
        {
            float hE[16], hO[16];
            #pragma unroll
            for (int r = 0; r < 16; ++r) { hE[r] = accE[r]; hO[r] = accO[r]; }
            bf16x8 E0h, E0l, E1h, E1l, O0h, O0l, O1h, O1l;
            build_bfrags(hE, E0h, E0l, E1h, E1l);
            build_bfrags(hO, O0h, O0l, O1h, O1l);
            nE = B2f; nO = B2f;
            nE = __builtin_amdgcn_mfma_f32_32x32x16_bf16(W2f[0], E0h, nE, 0, 0, 0);
            nE = __builtin_amdgcn_mfma_f32_32x32x16_bf16(W2f[0], E0l, nE, 0, 0, 0);
            nE = __builtin_amdgcn_mfma_f32_32x32x16_bf16(W2f[1], E1h, nE, 0, 0, 0);
            nE = __builtin_amdgcn_mfma_f32_32x32x16_bf16(W2f[1], E1l, nE, 0, 0, 0);
            nO = __builtin_amdgcn_mfma_f32_32x32x16_bf16(W2f[0], O0h, nO, 0, 0, 0);
            nO = __builtin_amdgcn_mfma_f32_32x32x16_bf16(W2f[0], O0l, nO, 0, 0, 0);
            nO = __builtin_amdgcn_mfma_f32_32x32x16_bf16(W2f[1], O1h, nO, 0, 0, 0);
            nO = __builtin_amdgcn_mfma_f32_32x32x16_bf16(W2f[1], O1l, nO, 0, 0, 0);
        }
        // ---- layer 3 ----
        f32x16 accE2, accO2;
        {
            float hE[16], hO[16];
            #pragma unroll
            for (int r = 0; r < 16; ++r) { hE[r] = nE[r]; hO[r] = nO[r]; }
            bf16x8 E0h, E0l, E1h, E1l, O0h, O0l, O1h, O1l;
            build_bfrags(hE, E0h, E0l, E1h, E1l);
            build_bfrags(hO, O0h, O0l, O1h, O1l);
            accE2 = B3f; accO2 = B3f;
            accE2 = __builtin_amdgcn_mfma_f32_32x32x16_bf16(W3f[0], E0h, accE2, 0, 0, 0);
            accE2 = __builtin_amdgcn_mfma_f32_32x32x16_bf16(W3f[0], E0l, accE2, 0, 0, 0);
            accE2 = __builtin_amdgcn_mfma_f32_32x32x16_bf16(W3f[1], E1h, accE2, 0, 0, 0);
            accE2 = __builtin_amdgcn_mfma_f32_32x32x16_bf16(W3f[1], E1l, accE2, 0, 0, 0);
            accO2 = __builtin_amdgcn_mfma_f32_32x32x16_bf16(W3f[0], O0h, accO2, 0, 0, 0);
            accO2 = __builtin_amdgcn_mfma_f32_32x32x16_bf16(W3f[0], O0l, accO2, 0, 0, 0);
            accO2 = __builtin_amdgcn_mfma_f32_32x32x16_bf16(W3f[1], O1h, accO2, 0, 0, 0);
            accO2 = __builtin_amdgcn_mfma_f32_32x32x16_bf16(W3f[1], O1l, accO2, 0, 0, 0);
        }

        // ---- final 1x32 dot in f32, cross-half reduce, store ----
        float sE = 0.f, sO = 0.f;
        #pragma unroll
        for (int r = 0; r < 16; ++r) {
            sE = fmaf(wlr[r], fmaxf(accE2[r], 0.f), sE);
            sO = fmaf(wlr[r], fmaxf(accO2[r], 0.f), sO);
        }
        unsigned px, py;
        swap32(__float_as_uint(sE), __float_as_uint(sE), px, py);
        float totE = __uint_as_float(px) + __uint_as_float(py) + blv;
        swap32(__float_as_uint(sO), __float_as_uint(sO), px, py);
        float totO = __uint_as_float(px) + __uint_as_float(py) + blv;

        if (lane < 32) out2[pt2] = make_float2(totE, totO);
    };

    compute_group(va, pt2a);
    compute_group(vb, pt2b);
}

extern "C" void kernel_launch(void* const* d_in, const int* in_sizes, int n_in,
                              void* d_out, int out_size, void* d_ws, size_t ws_size,
                              hipStream_t stream)
{
    const float* fm = (const float*)d_in[0];
    const float* z  = (const float*)d_in[1];
    const float* w1 = (const float*)d_in[2];
    const float* b1 = (const float*)d_in[3];
    const float* w2 = (const float*)d_in[4];
    const float* b2 = (const float*)d_in[5];
    const float* w3 = (const float*)d_in[6];
    const float* b3 = (const float*)d_in[7];
    const float* wl = (const float*)d_in[8];
    const float* bl = (const float*)d_in[9];
    float* out = (float*)d_out;

    fused_mlp_mfma<<<NBLK, BLOCK, 0, stream>>>(
        fm, z, w1, b1, w2, b2, w3, b3, wl, bl, out);
}

// Round 4
// 190.894 us; speedup vs baseline: 1.0070x; 1.0070x over previous
//
#include <hip/hip_runtime.h>

// FComb: fused pointwise 4-layer MLP over 96^3 points, bf16 MFMA, R4.
// Change vs R3: (a) split WEIGHTS hi+lo (setup-time) instead of activations
// (same error structure, half the per-layer pack glue); (b) register-pressure
// and codegen hygiene: no lambdas, no unions, no pointer-passed arrays, vb
// loads issued after va is consumed. Target: ~210 live VGPR, no spills.
// MFMA 32x32x16 layouts (verified by R2 pass):
//   A: row=lane&31, k=16*h+8*(lane>>5)+i ; B: same k per lane, col=lane&31
//   D: col=lane&31, row=(r&3)+8*(r>>2)+4*(lane>>5)

typedef float    f32x16 __attribute__((ext_vector_type(16)));
typedef short    bf16x8 __attribute__((ext_vector_type(8)));
typedef unsigned u32x4  __attribute__((ext_vector_type(4)));

constexpr int NPTS  = 96 * 96 * 96;   // 884736
constexpr int NP2   = NPTS / 2;       // float2 per channel
constexpr int BLOCK = 256;            // 4 waves
constexpr int GPW   = 2;              // 64-pt groups per wave
constexpr int NBLK  = 1728;           // 6912 waves * 2 * 64 = NPTS

__device__ __forceinline__ unsigned cvtpk(float lo, float hi) {
    unsigned d;
    asm("v_cvt_pk_bf16_f32 %0, %1, %2" : "=v"(d) : "v"(lo), "v"(hi));
    return d;
}
__device__ __forceinline__ float unlo(unsigned d) { return __uint_as_float(d << 16); }
__device__ __forceinline__ float unhi(unsigned d) { return __uint_as_float(d & 0xffff0000u); }

__device__ __forceinline__ bf16x8 mk4(unsigned a, unsigned b, unsigned c, unsigned d) {
    u32x4 u; u.x = a; u.y = b; u.z = c; u.w = d;
    return __builtin_bit_cast(bf16x8, u);
}

__device__ __forceinline__ void swap32(unsigned a, unsigned b, unsigned& x, unsigned& y) {
    auto r = __builtin_amdgcn_permlane32_swap(a, b, false, false);
    x = r[0]; y = r[1];
}

// Load 8 consecutive weights W[row][koff..koff+7], split hi+lo bf16.
__device__ __forceinline__ void load_wsplit(const float* __restrict__ W, int stride,
                                            int row, int koff, bf16x8& Hf, bf16x8& Lf) {
    const float2* p2 = reinterpret_cast<const float2*>(W + row * stride + koff);
    float2 q0 = p2[0], q1 = p2[1], q2 = p2[2], q3 = p2[3];
    unsigned h0 = cvtpk(q0.x, q0.y), h1 = cvtpk(q1.x, q1.y);
    unsigned h2 = cvtpk(q2.x, q2.y), h3 = cvtpk(q3.x, q3.y);
    unsigned l0 = cvtpk(q0.x - unlo(h0), q0.y - unhi(h0));
    unsigned l1 = cvtpk(q1.x - unlo(h1), q1.y - unhi(h1));
    unsigned l2 = cvtpk(q2.x - unlo(h2), q2.y - unhi(h2));
    unsigned l3 = cvtpk(q3.x - unlo(h3), q3.y - unhi(h3));
    Hf = mk4(h0, h1, h2, h3);
    Lf = mk4(l0, l1, l2, l3);
}

// relu + bf16-pack a D-layout f32x16 into the next layer's two B-frags.
__device__ __forceinline__ void pack_frags(const f32x16 acc, bf16x8& F0, bf16x8& F1) {
    unsigned p0 = cvtpk(fmaxf(acc[0],  0.f), fmaxf(acc[1],  0.f));
    unsigned p1 = cvtpk(fmaxf(acc[2],  0.f), fmaxf(acc[3],  0.f));
    unsigned p2 = cvtpk(fmaxf(acc[4],  0.f), fmaxf(acc[5],  0.f));
    unsigned p3 = cvtpk(fmaxf(acc[6],  0.f), fmaxf(acc[7],  0.f));
    unsigned p4 = cvtpk(fmaxf(acc[8],  0.f), fmaxf(acc[9],  0.f));
    unsigned p5 = cvtpk(fmaxf(acc[10], 0.f), fmaxf(acc[11], 0.f));
    unsigned p6 = cvtpk(fmaxf(acc[12], 0.f), fmaxf(acc[13], 0.f));
    unsigned p7 = cvtpk(fmaxf(acc[14], 0.f), fmaxf(acc[15], 0.f));
    unsigned a0, a1, b0, b1, c0, c1, d0, d1;
    swap32(p0, p2, a0, a1); swap32(p1, p3, b0, b1);
    swap32(p4, p6, c0, c1); swap32(p5, p7, d0, d1);
    F0 = mk4(a0, b0, a1, b1);
    F1 = mk4(c0, d0, c1, d1);
}

#define LAYER4(acc, WH0, WL0, WH1, WL1, F0, F1)                                   \
    acc = __builtin_amdgcn_mfma_f32_32x32x16_bf16(WH0, F0, acc, 0, 0, 0);         \
    acc = __builtin_amdgcn_mfma_f32_32x32x16_bf16(WL0, F0, acc, 0, 0, 0);         \
    acc = __builtin_amdgcn_mfma_f32_32x32x16_bf16(WH1, F1, acc, 0, 0, 0);         \
    acc = __builtin_amdgcn_mfma_f32_32x32x16_bf16(WL1, F1, acc, 0, 0, 0);

__global__ __launch_bounds__(BLOCK, 2)
void fused_mlp_mfma(const float* __restrict__ fm, const float* __restrict__ z,
                    const float* __restrict__ w1, const float* __restrict__ b1,
                    const float* __restrict__ w2, const float* __restrict__ b2,
                    const float* __restrict__ w3, const float* __restrict__ b3,
                    const float* __restrict__ wl, const float* __restrict__ bl,
                    float* __restrict__ out)
{
    const int lane = threadIdx.x & 63;
    const int wid  = blockIdx.x * (BLOCK / 64) + (threadIdx.x >> 6);
    const int hl   = lane >> 5;
    const int col  = lane & 31;
    const int koff = 8 * hl;

    const float2* __restrict__ fm2 = reinterpret_cast<const float2*>(fm);
    float2* __restrict__ out2      = reinterpret_cast<float2*>(out);

    const int g0   = wid * GPW;
    const int pt2a = (g0 + 0) * 32 + col;
    const int pt2b = (g0 + 1) * 32 + col;

    // ---- group-a input loads (16 x 8B, coalesced), in flight during setup ----
    float2 va[16];
    #pragma unroll
    for (int i = 0; i < 16; ++i) {
        const int ch = ((i < 8) ? i : (8 + i)) + koff;
        va[i] = fm2[ch * NP2 + pt2a];
    }

    // ---- weight frags, hi+lo split (12 frags, 48 VGPR) ----
    bf16x8 W1h0, W1l0, W1h1, W1l1, W2h0, W2l0, W2h1, W2l1, W3h0, W3l0, W3h1, W3l1;
    load_wsplit(w1, 38, col, 0  + koff, W1h0, W1l0);
    load_wsplit(w1, 38, col, 16 + koff, W1h1, W1l1);
    load_wsplit(w2, 32, col, 0  + koff, W2h0, W2l0);
    load_wsplit(w2, 32, col, 16 + koff, W2h1, W2l1);
    load_wsplit(w3, 32, col, 0  + koff, W3h0, W3l0);
    load_wsplit(w3, 32, col, 16 + koff, W3h1, W3l1);

    // ---- bias frags in D layout; z folded into b1 ----
    float zv0 = z[0], zv1 = z[1], zv2 = z[2], zv3 = z[3], zv4 = z[4], zv5 = z[5];
    f32x16 B1f, B2f, B3f;
    f32x16 wlr;
    #pragma unroll
    for (int r = 0; r < 16; ++r) {
        const int ch = (r & 3) + 8 * (r >> 2) + 4 * hl;
        float t = b1[ch];
        t = fmaf(w1[ch * 38 + 32], zv0, t);
        t = fmaf(w1[ch * 38 + 33], zv1, t);
        t = fmaf(w1[ch * 38 + 34], zv2, t);
        t = fmaf(w1[ch * 38 + 35], zv3, t);
        t = fmaf(w1[ch * 38 + 36], zv4, t);
        t = fmaf(w1[ch * 38 + 37], zv5, t);
        B1f[r] = t;
        B2f[r] = b2[ch];
        B3f[r] = b3[ch];
        wlr[r] = wl[ch];
    }
    const float blv = bl[0];

    // ================= group a =================
    // L1 B-frags straight from loads (lane already holds its k-channels).
    bf16x8 aE0 = mk4(cvtpk(va[0].x,  va[1].x),  cvtpk(va[2].x,  va[3].x),
                     cvtpk(va[4].x,  va[5].x),  cvtpk(va[6].x,  va[7].x));
    bf16x8 aE1 = mk4(cvtpk(va[8].x,  va[9].x),  cvtpk(va[10].x, va[11].x),
                     cvtpk(va[12].x, va[13].x), cvtpk(va[14].x, va[15].x));
    bf16x8 aO0 = mk4(cvtpk(va[0].y,  va[1].y),  cvtpk(va[2].y,  va[3].y),
                     cvtpk(va[4].y,  va[5].y),  cvtpk(va[6].y,  va[7].y));
    bf16x8 aO1 = mk4(cvtpk(va[8].y,  va[9].y),  cvtpk(va[10].y, va[11].y),
                     cvtpk(va[12].y, va[13].y), cvtpk(va[14].y, va[15].y));

    f32x16 accE = B1f, accO = B1f;
    LAYER4(accE, W1h0, W1l0, W1h1, W1l1, aE0, aE1)
    LAYER4(accO, W1h0, W1l0, W1h1, W1l1, aO0, aO1)

    // va is dead now -> issue group-b loads (reuse the registers).
    float2 vb[16];
    #pragma unroll
    for (int i = 0; i < 16; ++i) {
        const int ch = ((i < 8) ? i : (8 + i)) + koff;
        vb[i] = fm2[ch * NP2 + pt2b];
    }

    bf16x8 f0, f1, g0f, g1f;
    pack_frags(accE, f0, f1);
    pack_frags(accO, g0f, g1f);
    f32x16 nE = B2f, nO = B2f;
    LAYER4(nE, W2h0, W2l0, W2h1, W2l1, f0, f1)
    LAYER4(nO, W2h0, W2l0, W2h1, W2l1, g0f, g1f)

    pack_frags(nE, f0, f1);
    pack_frags(nO, g0f, g1f);
    accE = B3f; accO = B3f;
    LAYER4(accE, W3h0, W3l0, W3h1, W3l1, f0, f1)
    LAYER4(accO, W3h0, W3l0, W3h1, W3l1, g0f, g1f)

    float sE = 0.f, sO = 0.f;
    #pragma unroll
    for (int r = 0; r < 16; ++r) {
        sE = fmaf(wlr[r], fmaxf(accE[r], 0.f), sE);
        sO = fmaf(wlr[r], fmaxf(accO[r], 0.f), sO);
    }
    {
        unsigned px, py;
        swap32(__float_as_uint(sE), __float_as_uint(sE), px, py);
        float totE = __uint_as_float(px) + __uint_as_float(py) + blv;
        swap32(__float_as_uint(sO), __float_as_uint(sO), px, py);
        float totO = __uint_as_float(px) + __uint_as_float(py) + blv;
        if (lane < 32) out2[pt2a] = make_float2(totE, totO);
    }

    // ================= group b =================
    bf16x8 bE0 = mk4(cvtpk(vb[0].x,  vb[1].x),  cvtpk(vb[2].x,  vb[3].x),
                     cvtpk(vb[4].x,  vb[5].x),  cvtpk(vb[6].x,  vb[7].x));
    bf16x8 bE1 = mk4(cvtpk(vb[8].x,  vb[9].x),  cvtpk(vb[10].x, vb[11].x),
                     cvtpk(vb[12].x, vb[13].x), cvtpk(vb[14].x, vb[15].x));
    bf16x8 bO0 = mk4(cvtpk(vb[0].y,  vb[1].y),  cvtpk(vb[2].y,  vb[3].y),
                     cvtpk(vb[4].y,  vb[5].y),  cvtpk(vb[6].y,  vb[7].y));
    bf16x8 bO1 = mk4(cvtpk(vb[8].y,  vb[9].y),  cvtpk(vb[10].y, vb[11].y),
                     cvtpk(vb[12].y, vb[13].y), cvtpk(vb[14].y, vb[15].y));

    accE = B1f; accO = B1f;
    LAYER4(accE, W1h0, W1l0, W1h1, W1l1, bE0, bE1)
    LAYER4(accO, W1h0, W1l0, W1h1, W1l1, bO0, bO1)

    pack_frags(accE, f0, f1);
    pack_frags(accO, g0f, g1f);
    nE = B2f; nO = B2f;
    LAYER4(nE, W2h0, W2l0, W2h1, W2l1, f0, f1)
    LAYER4(nO, W2h0, W2l0, W2h1, W2l1, g0f, g1f)

    pack_frags(nE, f0, f1);
    pack_frags(nO, g0f, g1f);
    accE = B3f; accO = B3f;
    LAYER4(accE, W3h0, W3l0, W3h1, W3l1, f0, f1)
    LAYER4(accO, W3h0, W3l0, W3h1, W3l1, g0f, g1f)

    sE = 0.f; sO = 0.f;
    #pragma unroll
    for (int r = 0; r < 16; ++r) {
        sE = fmaf(wlr[r], fmaxf(accE[r], 0.f), sE);
        sO = fmaf(wlr[r], fmaxf(accO[r], 0.f), sO);
    }
    {
        unsigned px, py;
        swap32(__float_as_uint(sE), __float_as_uint(sE), px, py);
        float totE = __uint_as_float(px) + __uint_as_float(py) + blv;
        swap32(__float_as_uint(sO), __float_as_uint(sO), px, py);
        float totO = __uint_as_float(px) + __uint_as_float(py) + blv;
        if (lane < 32) out2[pt2b] = make_float2(totE, totO);
    }
}

extern "C" void kernel_launch(void* const* d_in, const int* in_sizes, int n_in,
                              void* d_out, int out_size, void* d_ws, size_t ws_size,
                              hipStream_t stream)
{
    const float* fm = (const float*)d_in[0];
    const float* z  = (const float*)d_in[1];
    const float* w1 = (const float*)d_in[2];
    const float* b1 = (const float*)d_in[3];
    const float* w2 = (const float*)d_in[4];
    const float* b2 = (const float*)d_in[5];
    const float* w3 = (const float*)d_in[6];
    const float* b3 = (const float*)d_in[7];
    const float* wl = (const float*)d_in[8];
    const float* bl = (const float*)d_in[9];
    float* out = (float*)d_out;

    fused_mlp_mfma<<<NBLK, BLOCK, 0, stream>>>(
        fm, z, w1, b1, w2, b2, w3, b3, wl, bl, out);
}